// Round 7
// baseline (318.878 us; speedup 1.0000x reference)
//
#include <hip/hip_runtime.h>

// MultiHeadAttention N=4 L=2048 E=1024 H=16 DK=64 on gfx950.
// Head split is reshape-based: head h of batch n = flat block (n*16+h)*131072,
// viewed as a 2048x64 row-major matrix. fp16 MFMA, f32 accumulate.

#define DEVI __device__ __forceinline__

typedef _Float16 half8 __attribute__((ext_vector_type(8)));
typedef _Float16 half4 __attribute__((ext_vector_type(4)));
typedef float f32x4 __attribute__((ext_vector_type(4)));

DEVI void gload_lds16(const void* g, void* l) {
    __builtin_amdgcn_global_load_lds(
        (const __attribute__((address_space(1))) void*)g,
        (__attribute__((address_space(3))) void*)l,
        16, 0, 0);
}

DEVI f32x4 zero4() { f32x4 z = {0.f, 0.f, 0.f, 0.f}; return z; }

#if __has_builtin(__builtin_amdgcn_exp2f)
DEVI float fast_exp2(float x) { return __builtin_amdgcn_exp2f(x); }
#else
DEVI float fast_exp2(float x) { return exp2f(x); }
#endif

// v_mfma_f32_16x16x16_f16: A,B = 4 f16 (2 VGPR), C/D = 4 f32.
#if __has_builtin(__builtin_amdgcn_mfma_f32_16x16x16f16)
DEVI f32x4 mfma16(half4 a, half4 b, f32x4 c) {
    return __builtin_amdgcn_mfma_f32_16x16x16f16(a, b, c, 0, 0, 0);
}
#else
DEVI f32x4 mfma16(half4 a, half4 b, f32x4 c) {
    asm volatile("v_mfma_f32_16x16x16_f16 %0, %1, %2, %0"
                 : "+v"(c) : "v"(a), "v"(b));
    return c;
}
#endif

// XOR-swizzled LDS read: logical (row, colbyte) in a [rows][64 f16] tile.
// Staged with pre-swizzled global source (rule #21, both-sides involution).
// Bank pattern verified conflict-free (PMC=0 on attn K path, rounds 3-6).
DEVI half8 lds_read8_swz(const _Float16* base, int row, int colbyte) {
    const char* p = (const char*)base;
    const int off = (row * 128 + colbyte) ^ ((row & 7) << 4);
    return *(const half8*)(p + off);
}

// ---------------- f32 -> f16 convert (vectorized) ----------------
__global__ __launch_bounds__(256) void f2h_kernel(const float* __restrict__ s,
                                                  _Float16* __restrict__ d) {
    const size_t i = (size_t)blockIdx.x * 256 + threadIdx.x;
    const float4 v = ((const float4*)s)[i];
    half4 h;
    h[0] = (_Float16)v.x; h[1] = (_Float16)v.y;
    h[2] = (_Float16)v.z; h[3] = (_Float16)v.w;
    ((half4*)d)[i] = h;
}

// ---------------- NT GEMM, m97 structure, chunked-XCD-swizzled 1-D grid ------
// 128x128 tile, BK=64, 4 waves each 64x64 (4x4 16x16 frags), global_load_lds
// width-16 staging with pre-swizzled source + swizzled ds_read_b128 (T2).
// Operand-SWAPPED MFMA (acc = mfma(b, a)): D holds C^T fragments, so each
// lane owns 4 CONSECUTIVE columns -> packed half4/float4 epilogue stores.
// MODE 0: fused QKV — A=x[8192][1024], B=[Wq;Wk;Wv][3072][1024],
//         C = three contiguous f16 [8192][1024] outputs (Q scaled by qscale).
// MODE 1: Wo — B=Wo[1024][1024], C f32 [8192][1024].
template<int MODE>
__global__ __launch_bounds__(256) void gemm_k(const _Float16* __restrict__ A,
                                              const _Float16* __restrict__ B,
                                              void* __restrict__ Cout,
                                              float qscale) {
    constexpr int NBLK = (MODE == 0) ? 24 : 8;   // N/128 column-blocks
    constexpr int CPX  = (MODE == 0) ? 192 : 64; // blocks per XCD chunk (nwg/8)
    alignas(16) __shared__ _Float16 As[128 * 64];
    alignas(16) __shared__ _Float16 Bs[128 * 64];
    const int t = threadIdx.x;
    const int lane = t & 63;
    const int w = t >> 6;
    const int wr = (w >> 1) * 64;
    const int wc = (w & 1) * 64;
    // chunked XCD swizzle (T1): consecutive work ids stay on one XCD's L2
    const int nid = (blockIdx.x & 7) * CPX + (blockIdx.x >> 3);
    const int bn = (nid % NBLK) * 128;
    const int bm = (nid / NBLK) * 128;
    const int r16 = lane & 15;
    const int q4 = lane >> 4;
    const int sr = t >> 3;                       // staging row within 32-row chunk
    const int sc8 = ((t & 7) ^ (sr & 7)) * 8;    // pre-swizzled staging col (elems)

    f32x4 acc[4][4];
    #pragma unroll
    for (int mi = 0; mi < 4; ++mi)
        #pragma unroll
        for (int ni = 0; ni < 4; ++ni)
            acc[mi][ni] = zero4();

    for (int kt = 0; kt < 1024; kt += 64) {
        #pragma unroll
        for (int i = 0; i < 4; ++i) {
            gload_lds16(A + (size_t)(bm + i * 32 + sr) * 1024 + kt + sc8, &As[i * 2048 + t * 8]);
            gload_lds16(B + (size_t)(bn + i * 32 + sr) * 1024 + kt + sc8, &Bs[i * 2048 + t * 8]);
        }
        __syncthreads();
        #pragma unroll
        for (int kk = 0; kk < 2; ++kk) {
            half8 a[4], b[4];
            #pragma unroll
            for (int mi = 0; mi < 4; ++mi)
                a[mi] = lds_read8_swz(As, wr + mi * 16 + r16, (kk * 32 + q4 * 8) * 2);
            #pragma unroll
            for (int ni = 0; ni < 4; ++ni)
                b[ni] = lds_read8_swz(Bs, wc + ni * 16 + r16, (kk * 32 + q4 * 8) * 2);
            // swapped operands: D = C^T fragment (rows = n, cols = m)
            #pragma unroll
            for (int mi = 0; mi < 4; ++mi)
                #pragma unroll
                for (int ni = 0; ni < 4; ++ni)
                    acc[mi][ni] = __builtin_amdgcn_mfma_f32_16x16x32_f16(b[ni], a[mi], acc[mi][ni], 0, 0, 0);
        }
        __syncthreads();
    }
    // C^T frag: lane holds m = r16 (fixed), n = q4*4 + i (4 consecutive cols).
    if (MODE == 0) {
        const int which = bn >> 10;            // 0=Q 1=K 2=V
        const int cb2 = bn & 1023;
        const float alpha = (which == 0) ? qscale : 1.0f;
        _Float16* C = (_Float16*)Cout + (size_t)which * 8388608;
        #pragma unroll
        for (int mi = 0; mi < 4; ++mi) {
            const int row = bm + wr + mi * 16 + r16;
            #pragma unroll
            for (int ni = 0; ni < 4; ++ni) {
                const int col0 = cb2 + wc + ni * 16 + q4 * 4;
                half4 ov;
                #pragma unroll
                for (int i = 0; i < 4; ++i)
                    ov[i] = (_Float16)(acc[mi][ni][i] * alpha);
                *(half4*)&C[(size_t)row * 1024 + col0] = ov;
            }
        }
    } else {
        float* C = (float*)Cout;
        #pragma unroll
        for (int mi = 0; mi < 4; ++mi) {
            const int row = bm + wr + mi * 16 + r16;
            #pragma unroll
            for (int ni = 0; ni < 4; ++ni) {
                const int col0 = bn + wc + ni * 16 + q4 * 4;
                *(f32x4*)&C[(size_t)row * 1024 + col0] = acc[mi][ni];
            }
        }
    }
}

// ---------------- V repack: per head, per 64-kv tile -> V4[a=16][d=64][j=4] --
// V4[h][kt][a][d][j] = V[h][kt*64 + 4a + j][d]. Makes attn's PV b64 reads
// bank-linear (conflict-free, PMC-verified round 6) and staging contiguous.
__global__ __launch_bounds__(256) void repack_v(const _Float16* __restrict__ V,
                                                _Float16* __restrict__ V4) {
    __shared__ unsigned short lds[64 * 65];
    const int t = threadIdx.x;
    const int kt = blockIdx.x;                 // 32 tiles of 64 kv-rows
    const size_t hb = (size_t)blockIdx.y * 131072;
    const int r = t >> 2;
    const int c0 = (t & 3) * 16;
    const unsigned short* Vi = (const unsigned short*)V;
    #pragma unroll
    for (int jj = 0; jj < 2; ++jj) {
        union { uint4 u; unsigned short s[8]; } tmp;
        tmp.u = *(const uint4*)&Vi[hb + (size_t)(kt * 64 + r) * 64 + c0 + jj * 8];
        #pragma unroll
        for (int e = 0; e < 8; ++e)
            lds[r * 65 + c0 + jj * 8 + e] = tmp.s[e];
    }
    __syncthreads();
    const size_t ob = hb + (size_t)kt * 4096;
    const unsigned short* ls = lds;
    #pragma unroll
    for (int h = 0; h < 2; ++h) {
        half8 v;
        #pragma unroll
        for (int e = 0; e < 8; ++e) {
            const int idx = t * 16 + h * 8 + e;
            const int a = idx >> 8;
            const int d = (idx >> 2) & 63;
            const int j = idx & 3;
            unsigned short u = ls[(4 * a + j) * 65 + d];
            v[e] = *(const _Float16*)&u;
        }
        *(half8*)&V4[ob + t * 16 + h * 8] = v;
    }
}

// ---------------- Flash attention: per (head, Q-tile of 128 rows) ----------------
// 4 waves x 32 Q-rows, KBLK=64, double-buffered K/V staging (2-phase pipeline),
// ONE barrier per tile. Swapped QK^T (S^T = mfma(K,Q)) puts P^T in exactly the
// B-operand fragment layout of v_mfma_f32_16x16x16_f16, so P NEVER touches LDS.
// V comes pre-packed as V4[a][d][j] so the PV A-operand b64 reads are
// bank-linear (no swizzle, no conflicts). Softmax-lite, single reduce at end.
__global__ __launch_bounds__(256) void attn_kernel(const _Float16* __restrict__ Q,
                                                   const _Float16* __restrict__ K,
                                                   const _Float16* __restrict__ V4,
                                                   _Float16* __restrict__ O) {
    alignas(16) __shared__ _Float16 Ks[2][64 * 64];
    alignas(16) __shared__ _Float16 Vs[2][64 * 64];
    const int t = threadIdx.x;
    const int lane = t & 63;
    const int w = t >> 6;
    const int nid = (blockIdx.x & 7) * 128 + (blockIdx.x >> 3);  // chunked swizzle
    const size_t hb = (size_t)(nid >> 4) * 131072;     // head base (64 heads)
    const int qt = nid & 15;                           // 16 Q-tiles per head
    const int r16 = lane & 15;
    const int q4 = lane >> 4;
    const int sr = t >> 3;
    const int sc = t & 7;

    // Q fragments in registers (Q pre-scaled by log2e/sqrt(dk) in its GEMM).
    half8 aq[2][2];
    const int q0 = qt * 128 + w * 32;
    #pragma unroll
    for (int mi = 0; mi < 2; ++mi)
        #pragma unroll
        for (int kk = 0; kk < 2; ++kk)
            aq[mi][kk] = *(const half8*)&Q[hb + (size_t)(q0 + mi * 16 + r16) * 64 + kk * 32 + q4 * 8];

    f32x4 o[4][2];         // O^T accumulator: [ni = d-block][mi = q-block]
    float lsum[2] = {0.f, 0.f};
    #pragma unroll
    for (int ni = 0; ni < 4; ++ni)
        #pragma unroll
        for (int mi = 0; mi < 2; ++mi)
            o[ni][mi] = zero4();

    // K staged with pre-swizzled source (conflict-free swizzled b128 reads);
    // V4 staged linearly (tile chunk is contiguous 8KB).
    const int R0 = sr, R1 = 32 + sr;
    const int scs0 = (sc ^ (R0 & 7)) * 8;
    const int scs1 = (sc ^ (R1 & 7)) * 8;

    {   // prologue: stage tile 0 into buffer 0
        gload_lds16(&K[hb + (size_t)R0 * 64 + scs0],  &Ks[0][t * 8]);
        gload_lds16(&K[hb + (size_t)R1 * 64 + scs1],  &Ks[0][2048 + t * 8]);
        gload_lds16(&V4[hb + t * 8],                  &Vs[0][t * 8]);
        gload_lds16(&V4[hb + 2048 + t * 8],           &Vs[0][2048 + t * 8]);
    }
    __syncthreads();

    int pb = 0;
    for (int kt = 0; kt < 32; ++kt) {
        // issue next tile's loads into the other buffer (retired by the
        // end-of-loop __syncthreads' implicit vmcnt(0) drain)
        if (kt + 1 < 32) {
            const size_t tb = hb + (size_t)(kt + 1) * 4096;
            gload_lds16(&K[tb + (size_t)R0 * 64 + scs0],  &Ks[pb ^ 1][t * 8]);
            gload_lds16(&K[tb + (size_t)R1 * 64 + scs1],  &Ks[pb ^ 1][2048 + t * 8]);
            gload_lds16(&V4[tb + t * 8],                  &Vs[pb ^ 1][t * 8]);
            gload_lds16(&V4[tb + 2048 + t * 8],           &Vs[pb ^ 1][2048 + t * 8]);
        }

        // S^T = K Q^T: D[row=kv][col=q]; lane holds S^T[16ki+4q4+i][16mi+r16]
        f32x4 sT[4][2];
        #pragma unroll
        for (int ki = 0; ki < 4; ++ki)
            #pragma unroll
            for (int mi = 0; mi < 2; ++mi)
                sT[ki][mi] = zero4();
        __builtin_amdgcn_s_setprio(1);
        #pragma unroll
        for (int kk = 0; kk < 2; ++kk) {
            half8 ak[4];
            #pragma unroll
            for (int ki = 0; ki < 4; ++ki)
                ak[ki] = lds_read8_swz(Ks[pb], ki * 16 + r16, (kk * 32 + q4 * 8) * 2);
            #pragma unroll
            for (int ki = 0; ki < 4; ++ki)
                #pragma unroll
                for (int mi = 0; mi < 2; ++mi)
                    sT[ki][mi] = __builtin_amdgcn_mfma_f32_16x16x32_f16(ak[ki], aq[mi][kk], sT[ki][mi], 0, 0, 0);
        }
        __builtin_amdgcn_s_setprio(0);

        // softmax-lite fully in-register: p = 2^s, row sums, pack to f16.
        // pT[ki][mi] is the ready-made 16x16x16 B-operand: B[n=q=r16][k=4q4+j].
        half4 pT[4][2];
        #pragma unroll
        for (int ki = 0; ki < 4; ++ki)
            #pragma unroll
            for (int mi = 0; mi < 2; ++mi) {
                const float p0 = fast_exp2(sT[ki][mi][0]);
                const float p1 = fast_exp2(sT[ki][mi][1]);
                const float p2 = fast_exp2(sT[ki][mi][2]);
                const float p3 = fast_exp2(sT[ki][mi][3]);
                lsum[mi] += (p0 + p1) + (p2 + p3);
                half4 pv;
                pv[0] = (_Float16)p0; pv[1] = (_Float16)p1;
                pv[2] = (_Float16)p2; pv[3] = (_Float16)p3;
                pT[ki][mi] = pv;
            }

        // O^T += V^T P^T: A-frag = V4 b64 read (lane: Vt[d=16ni+r16][kv=16ki+4q4+j])
        __builtin_amdgcn_s_setprio(1);
        #pragma unroll
        for (int ki = 0; ki < 4; ++ki)
            #pragma unroll
            for (int ni = 0; ni < 4; ++ni) {
                const half4 av = *(const half4*)&Vs[pb][(ki * 4 + q4) * 256 + (ni * 16 + r16) * 4];
                #pragma unroll
                for (int mi = 0; mi < 2; ++mi)
                    o[ni][mi] = mfma16(av, pT[ki][mi], o[ni][mi]);
            }
        __builtin_amdgcn_s_setprio(0);

        __syncthreads();   // drains prefetch vmcnt + guards K/V buffer reuse
        pb ^= 1;
    }

    // final row-sum reduce across the 4 q4 groups -> shfl_xor 16, 32.
    float inv[2];
    #pragma unroll
    for (int mi = 0; mi < 2; ++mi) {
        float l = lsum[mi];
        l += __shfl_xor(l, 16);
        l += __shfl_xor(l, 32);
        inv[mi] = 1.f / l;
    }
    // O^T frag (ni,mi): rows d = 16ni+4q4+i, col q = q0+16mi+r16 ->
    // lane owns 4 consecutive d at one q: packed 8B store.
    #pragma unroll
    for (int mi = 0; mi < 2; ++mi) {
        const int q = q0 + mi * 16 + r16;
        #pragma unroll
        for (int ni = 0; ni < 4; ++ni) {
            half4 ov;
            #pragma unroll
            for (int i = 0; i < 4; ++i)
                ov[i] = (_Float16)(o[ni][mi][i] * inv[mi]);
            *(half4*)&O[hb + (size_t)q * 64 + ni * 16 + q4 * 4] = ov;
        }
    }
}

// ---------------- launcher ----------------
extern "C" void kernel_launch(void* const* d_in, const int* in_sizes, int n_in,
                              void* d_out, int out_size, void* d_ws, size_t ws_size,
                              hipStream_t stream) {
    const float* x  = (const float*)d_in[0];
    const float* Wq = (const float*)d_in[1];
    const float* Wk = (const float*)d_in[2];
    const float* Wv = (const float*)d_in[3];
    const float* Wo = (const float*)d_in[4];

    const size_t XSZ = (size_t)8192 * 1024;   // 8388608 elements
    const size_t WSZ = (size_t)1024 * 1024;

    // workspace layout (f16 elements); total = 88 MB
    // NOTE: wqh/wkh/wvh contiguous (fused B), qh/kh/vh contiguous (fused C).
    _Float16* ws  = (_Float16*)d_ws;
    _Float16* xh  = ws;                 // x f16; reused as V4 after V-GEMM
    _Float16* wqh = ws + XSZ;
    _Float16* wkh = wqh + WSZ;
    _Float16* wvh = wkh + WSZ;
    _Float16* woh = wvh + WSZ;
    _Float16* qh  = woh + WSZ;
    _Float16* kh  = qh + XSZ;
    _Float16* vh  = kh + XSZ;
    _Float16* aoh = vh + XSZ;
    _Float16* v4h = xh;                 // alias: x dead after QKV projection

    f2h_kernel<<<XSZ / 4 / 256, 256, 0, stream>>>(x,  xh);
    f2h_kernel<<<WSZ / 4 / 256, 256, 0, stream>>>(Wq, wqh);
    f2h_kernel<<<WSZ / 4 / 256, 256, 0, stream>>>(Wk, wkh);
    f2h_kernel<<<WSZ / 4 / 256, 256, 0, stream>>>(Wv, wvh);
    f2h_kernel<<<WSZ / 4 / 256, 256, 0, stream>>>(Wo, woh);

    // Q scale: (1/sqrt(64)) * log2(e) so attention can use exp2 directly
    const float qscale = 0.125f * 1.44269504088896340736f;

    gemm_k<0><<<1536, 256, 0, stream>>>(xh, wqh, (void*)qh, qscale);  // fused QKV

    repack_v<<<dim3(32, 64), 256, 0, stream>>>(vh, v4h);

    attn_kernel<<<1024, 256, 0, stream>>>(qh, kh, v4h, aoh);

    gemm_k<1><<<512, 256, 0, stream>>>(aoh, woh, d_out, 1.0f);        // Wo, f32 out
    (void)in_sizes; (void)n_in; (void)out_size; (void)ws_size;
}

// Round 8
// 312.822 us; speedup vs baseline: 1.0194x; 1.0194x over previous
//
#include <hip/hip_runtime.h>

// MultiHeadAttention N=4 L=2048 E=1024 H=16 DK=64 on gfx950.
// Head split is reshape-based: head h of batch n = flat block (n*16+h)*131072,
// viewed as a 2048x64 row-major matrix. fp16 MFMA, f32 accumulate.

#define DEVI __device__ __forceinline__

typedef _Float16 half8 __attribute__((ext_vector_type(8)));
typedef _Float16 half4 __attribute__((ext_vector_type(4)));
typedef float f32x4 __attribute__((ext_vector_type(4)));

DEVI void gload_lds16(const void* g, void* l) {
    __builtin_amdgcn_global_load_lds(
        (const __attribute__((address_space(1))) void*)g,
        (__attribute__((address_space(3))) void*)l,
        16, 0, 0);
}

DEVI f32x4 zero4() { f32x4 z = {0.f, 0.f, 0.f, 0.f}; return z; }

#if __has_builtin(__builtin_amdgcn_exp2f)
DEVI float fast_exp2(float x) { return __builtin_amdgcn_exp2f(x); }
#else
DEVI float fast_exp2(float x) { return exp2f(x); }
#endif

// v_mfma_f32_16x16x16_f16: A,B = 4 f16 (2 VGPR), C/D = 4 f32.
#if __has_builtin(__builtin_amdgcn_mfma_f32_16x16x16f16)
DEVI f32x4 mfma16(half4 a, half4 b, f32x4 c) {
    return __builtin_amdgcn_mfma_f32_16x16x16f16(a, b, c, 0, 0, 0);
}
#else
DEVI f32x4 mfma16(half4 a, half4 b, f32x4 c) {
    asm volatile("v_mfma_f32_16x16x16_f16 %0, %1, %2, %0"
                 : "+v"(c) : "v"(a), "v"(b));
    return c;
}
#endif

// XOR-swizzled LDS read: logical (row, colbyte) in a [rows][64 f16] tile.
// Paired with pre-swizzled global_load_lds source (rule #21 involution).
// Bank pattern PMC-verified conflict-free (attn K path, rounds 3-7).
DEVI half8 lds_read8_swz(const _Float16* base, int row, int colbyte) {
    const char* p = (const char*)base;
    const int off = (row * 128 + colbyte) ^ ((row & 7) << 4);
    return *(const half8*)(p + off);
}

// ---------------- f32 -> f16 convert (vectorized) ----------------
__global__ __launch_bounds__(256) void f2h_kernel(const float* __restrict__ s,
                                                  _Float16* __restrict__ d) {
    const size_t i = (size_t)blockIdx.x * 256 + threadIdx.x;
    const float4 v = ((const float4*)s)[i];
    half4 h;
    h[0] = (_Float16)v.x; h[1] = (_Float16)v.y;
    h[2] = (_Float16)v.z; h[3] = (_Float16)v.w;
    ((half4*)d)[i] = h;
}

// ---------------- QKV GEMM: faithful 8-phase 256x256 template (T2+T3+T4+T5) --
// C[m,n] = alpha * sum_k A[m,k]*B[n,k]; A=x[8192][1024], B=[Wq;Wk;Wv][3072][1024],
// C = three contiguous f16 [8192][1024] outputs (Q block scaled by qscale).
// BM=BN=256, BK=64, 512 thr = 8 waves (2M x 4N), per-wave 128x64 output.
// LDS 128KB: [dbuf][half][128x64] for A and B; halves are 128-row slabs, so
// wave (wm,wn) touches ONLY A-half wm and B-half wn>>1.
// Per K-tile: 4 phases, each {ds_read quadrant || stage 1 half of tile t+1 ||
// barrier; lgkm(0); setprio; 16 MFMA; barrier}. Gate: vmcnt(2) once per tile
// (the just-issued next-tile half stays in flight; never drain mid-loop).
__global__ __launch_bounds__(512, 2) void gemm8(const _Float16* __restrict__ A,
                                                const _Float16* __restrict__ B,
                                                _Float16* __restrict__ Cout,
                                                float qscale) {
    alignas(16) __shared__ _Float16 Al[2][2][128 * 64];
    alignas(16) __shared__ _Float16 Bl[2][2][128 * 64];
    const int t = threadIdx.x;
    const int lane = t & 63;
    const int w = t >> 6;              // 0..7
    const int wm = w >> 2;             // 0..1 -> A-half / 128-row slab
    const int wn = w & 3;              // 0..3 -> 64-col slab
    const int bh = wn >> 1;            // B-half
    const int brow0 = (wn & 1) * 64;   // row base inside B-half
    const int r16 = lane & 15;
    const int q4 = lane >> 4;
    // chunked XCD swizzle: 384 blocks, 48 per XCD; consecutive nids share bm
    const int nid = (blockIdx.x & 7) * 48 + (blockIdx.x >> 3);
    const int bn = (nid % 12) * 256;
    const int bm = (nid / 12) * 256;
    const int srow = t >> 3;                       // staging row 0..63
    const int scol = ((t & 7) ^ (srow & 7)) * 8;   // pre-swizzled col (elems)

    f32x4 acc[8][4];
    #pragma unroll
    for (int mi = 0; mi < 8; ++mi)
        #pragma unroll
        for (int ni = 0; ni < 4; ++ni)
            acc[mi][ni] = zero4();

    // stage one half-tile (2 gload_lds): kind 0=A:h0 1=B:h0 2=A:h1 3=B:h1
    auto stageH = [&](int kind, int ktile) {
        const int d = ktile & 1;
        const int h = kind >> 1;
        const bool isB = kind & 1;
        const _Float16* src = isB ? B : A;
        const int baseRow = (isB ? bn : bm) + h * 128;
        _Float16* dst = isB ? &Bl[d][h][0] : &Al[d][h][0];
        #pragma unroll
        for (int i = 0; i < 2; ++i)
            gload_lds16(src + (size_t)(baseRow + i * 64 + srow) * 1024 + ktile * 64 + scol,
                        dst + i * 4096 + t * 8);
    };

    // prologue: tile 0 fully staged (8 loads in flight)
    stageH(0, 0); stageH(1, 0); stageH(2, 0); stageH(3, 0);

    for (int kt = 0; kt < 16; ++kt) {
        const int d = kt & 1;
        const _Float16* Ah = &Al[d][wm][0];
        const _Float16* Bh = &Bl[d][bh][0];
        const bool pf = (kt < 15);
        half8 af[4], bf[4];

        // ---- phase 0: quadrant (m0-3, kk0); gate tile kt ----
        if (pf) stageH(0, kt + 1);
        if (pf) asm volatile("s_waitcnt vmcnt(2)" ::: "memory");
        else    asm volatile("s_waitcnt vmcnt(0)" ::: "memory");
        __builtin_amdgcn_sched_barrier(0);
        __builtin_amdgcn_s_barrier();
        __builtin_amdgcn_sched_barrier(0);
        #pragma unroll
        for (int mi = 0; mi < 4; ++mi)
            af[mi] = lds_read8_swz(Ah, mi * 16 + r16, q4 * 16);
        #pragma unroll
        for (int ni = 0; ni < 4; ++ni)
            bf[ni] = lds_read8_swz(Bh, brow0 + ni * 16 + r16, q4 * 16);
        asm volatile("s_waitcnt lgkmcnt(0)" ::: "memory");
        __builtin_amdgcn_sched_barrier(0);
        __builtin_amdgcn_s_setprio(1);
        #pragma unroll
        for (int mi = 0; mi < 4; ++mi)
            #pragma unroll
            for (int ni = 0; ni < 4; ++ni)
                acc[mi][ni] = __builtin_amdgcn_mfma_f32_16x16x32_f16(af[mi], bf[ni], acc[mi][ni], 0, 0, 0);
        __builtin_amdgcn_s_setprio(0);
        __builtin_amdgcn_s_barrier();

        // ---- phase 1: quadrant (m4-7, kk0); bf reused ----
        #pragma unroll
        for (int mi = 0; mi < 4; ++mi)
            af[mi] = lds_read8_swz(Ah, (4 + mi) * 16 + r16, q4 * 16);
        if (pf) stageH(1, kt + 1);
        __builtin_amdgcn_s_barrier();
        asm volatile("s_waitcnt lgkmcnt(0)" ::: "memory");
        __builtin_amdgcn_sched_barrier(0);
        __builtin_amdgcn_s_setprio(1);
        #pragma unroll
        for (int mi = 0; mi < 4; ++mi)
            #pragma unroll
            for (int ni = 0; ni < 4; ++ni)
                acc[4 + mi][ni] = __builtin_amdgcn_mfma_f32_16x16x32_f16(af[mi], bf[ni], acc[4 + mi][ni], 0, 0, 0);
        __builtin_amdgcn_s_setprio(0);
        __builtin_amdgcn_s_barrier();

        // ---- phase 2: quadrant (m0-3, kk1) ----
        #pragma unroll
        for (int mi = 0; mi < 4; ++mi)
            af[mi] = lds_read8_swz(Ah, mi * 16 + r16, 64 + q4 * 16);
        #pragma unroll
        for (int ni = 0; ni < 4; ++ni)
            bf[ni] = lds_read8_swz(Bh, brow0 + ni * 16 + r16, 64 + q4 * 16);
        if (pf) stageH(2, kt + 1);
        __builtin_amdgcn_s_barrier();
        asm volatile("s_waitcnt lgkmcnt(0)" ::: "memory");
        __builtin_amdgcn_sched_barrier(0);
        __builtin_amdgcn_s_setprio(1);
        #pragma unroll
        for (int mi = 0; mi < 4; ++mi)
            #pragma unroll
            for (int ni = 0; ni < 4; ++ni)
                acc[mi][ni] = __builtin_amdgcn_mfma_f32_16x16x32_f16(af[mi], bf[ni], acc[mi][ni], 0, 0, 0);
        __builtin_amdgcn_s_setprio(0);
        __builtin_amdgcn_s_barrier();

        // ---- phase 3: quadrant (m4-7, kk1); bf reused ----
        #pragma unroll
        for (int mi = 0; mi < 4; ++mi)
            af[mi] = lds_read8_swz(Ah, (4 + mi) * 16 + r16, 64 + q4 * 16);
        if (pf) stageH(3, kt + 1);
        __builtin_amdgcn_s_barrier();
        asm volatile("s_waitcnt lgkmcnt(0)" ::: "memory");
        __builtin_amdgcn_sched_barrier(0);
        __builtin_amdgcn_s_setprio(1);
        #pragma unroll
        for (int mi = 0; mi < 4; ++mi)
            #pragma unroll
            for (int ni = 0; ni < 4; ++ni)
                acc[4 + mi][ni] = __builtin_amdgcn_mfma_f32_16x16x32_f16(af[mi], bf[ni], acc[4 + mi][ni], 0, 0, 0);
        __builtin_amdgcn_s_setprio(0);
        __builtin_amdgcn_s_barrier();   // tile-end: readers of dbuf d done
    }

    // epilogue: round-4 proven layout. D frag: col = +r16, row = +q4*4+i.
    const int which = bn >> 10;            // 0=Q 1=K 2=V (bn is 256-aligned)
    const int cb2 = bn & 1023;
    const float alpha = (which == 0) ? qscale : 1.0f;
    _Float16* C = Cout + (size_t)which * 8388608;
    #pragma unroll
    for (int mi = 0; mi < 8; ++mi) {
        const int row = bm + wm * 128 + mi * 16 + q4 * 4;
        #pragma unroll
        for (int ni = 0; ni < 4; ++ni) {
            const int col = cb2 + wn * 64 + ni * 16 + r16;
            #pragma unroll
            for (int i = 0; i < 4; ++i)
                C[(size_t)(row + i) * 1024 + col] = (_Float16)(acc[mi][ni][i] * alpha);
        }
    }
}

// ---------------- Wo GEMM: round-4 proven m97-structure (exact revert) -------
// A=attn_out[8192][1024], B=Wo[1024][1024], C f32 [8192][1024].
__global__ __launch_bounds__(256) void gemm_wo(const _Float16* __restrict__ A,
                                               const _Float16* __restrict__ B,
                                               float* __restrict__ C) {
    alignas(16) __shared__ _Float16 As[128 * 64];
    alignas(16) __shared__ _Float16 Bs[128 * 64];
    const int t = threadIdx.x;
    const int lane = t & 63;
    const int w = t >> 6;
    const int wr = (w >> 1) * 64;
    const int wc = (w & 1) * 64;
    const int nid = (blockIdx.x & 7) * 64 + (blockIdx.x >> 3);
    const int bn = (nid % 8) * 128;
    const int bm = (nid / 8) * 128;
    const int r16 = lane & 15;
    const int q4 = lane >> 4;
    const int sr = t >> 3;
    const int sc8 = (t & 7) * 8;

    f32x4 acc[4][4];
    #pragma unroll
    for (int mi = 0; mi < 4; ++mi)
        #pragma unroll
        for (int ni = 0; ni < 4; ++ni)
            acc[mi][ni] = zero4();

    for (int kt = 0; kt < 1024; kt += 64) {
        #pragma unroll
        for (int i = 0; i < 4; ++i) {
            gload_lds16(A + (size_t)(bm + i * 32 + sr) * 1024 + kt + sc8, &As[i * 2048 + t * 8]);
            gload_lds16(B + (size_t)(bn + i * 32 + sr) * 1024 + kt + sc8, &Bs[i * 2048 + t * 8]);
        }
        __syncthreads();
        #pragma unroll
        for (int kk = 0; kk < 2; ++kk) {
            half8 a[4], b[4];
            #pragma unroll
            for (int mi = 0; mi < 4; ++mi)
                a[mi] = *(const half8*)&As[(wr + mi * 16 + r16) * 64 + kk * 32 + q4 * 8];
            #pragma unroll
            for (int ni = 0; ni < 4; ++ni)
                b[ni] = *(const half8*)&Bs[(wc + ni * 16 + r16) * 64 + kk * 32 + q4 * 8];
            #pragma unroll
            for (int mi = 0; mi < 4; ++mi)
                #pragma unroll
                for (int ni = 0; ni < 4; ++ni)
                    acc[mi][ni] = __builtin_amdgcn_mfma_f32_16x16x32_f16(a[mi], b[ni], acc[mi][ni], 0, 0, 0);
        }
        __syncthreads();
    }
    #pragma unroll
    for (int mi = 0; mi < 4; ++mi) {
        const int row = bm + wr + mi * 16 + q4 * 4;
        #pragma unroll
        for (int ni = 0; ni < 4; ++ni) {
            const int col = bn + wc + ni * 16 + r16;
            #pragma unroll
            for (int i = 0; i < 4; ++i)
                C[(size_t)(row + i) * 1024 + col] = acc[mi][ni][i];
        }
    }
}

// ---------------- V repack: per head, per 64-kv tile -> V4[a=16][d=64][j=4] --
// V4[h][kt][a][d][j] = V[h][kt*64 + 4a + j][d]. Makes attn's PV b64 reads
// bank-linear (conflict-free, PMC-verified round 6) and staging contiguous.
__global__ __launch_bounds__(256) void repack_v(const _Float16* __restrict__ V,
                                                _Float16* __restrict__ V4) {
    __shared__ unsigned short lds[64 * 65];
    const int t = threadIdx.x;
    const int kt = blockIdx.x;                 // 32 tiles of 64 kv-rows
    const size_t hb = (size_t)blockIdx.y * 131072;
    const int r = t >> 2;
    const int c0 = (t & 3) * 16;
    const unsigned short* Vi = (const unsigned short*)V;
    #pragma unroll
    for (int jj = 0; jj < 2; ++jj) {
        union { uint4 u; unsigned short s[8]; } tmp;
        tmp.u = *(const uint4*)&Vi[hb + (size_t)(kt * 64 + r) * 64 + c0 + jj * 8];
        #pragma unroll
        for (int e = 0; e < 8; ++e)
            lds[r * 65 + c0 + jj * 8 + e] = tmp.s[e];
    }
    __syncthreads();
    const size_t ob = hb + (size_t)kt * 4096;
    const unsigned short* ls = lds;
    #pragma unroll
    for (int h = 0; h < 2; ++h) {
        half8 v;
        #pragma unroll
        for (int e = 0; e < 8; ++e) {
            const int idx = t * 16 + h * 8 + e;
            const int a = idx >> 8;
            const int d = (idx >> 2) & 63;
            const int j = idx & 3;
            unsigned short u = ls[(4 * a + j) * 65 + d];
            v[e] = *(const _Float16*)&u;
        }
        *(half8*)&V4[ob + t * 16 + h * 8] = v;
    }
}

// ---------------- Flash attention: per (head, Q-tile of 128 rows) ----------------
// 4 waves x 32 Q-rows, KBLK=64, double-buffered K/V staging (2-phase pipeline),
// ONE barrier per tile. Swapped QK^T (S^T = mfma(K,Q)) puts P^T in exactly the
// B-operand fragment layout of v_mfma_f32_16x16x16_f16, so P NEVER touches LDS.
// V pre-packed as V4[a][d][j] -> PV b64 reads bank-linear (0 conflicts).
__global__ __launch_bounds__(256) void attn_kernel(const _Float16* __restrict__ Q,
                                                   const _Float16* __restrict__ K,
                                                   const _Float16* __restrict__ V4,
                                                   _Float16* __restrict__ O) {
    alignas(16) __shared__ _Float16 Ks[2][64 * 64];
    alignas(16) __shared__ _Float16 Vs[2][64 * 64];
    const int t = threadIdx.x;
    const int lane = t & 63;
    const int w = t >> 6;
    const int nid = (blockIdx.x & 7) * 128 + (blockIdx.x >> 3);  // chunked swizzle
    const size_t hb = (size_t)(nid >> 4) * 131072;     // head base (64 heads)
    const int qt = nid & 15;                           // 16 Q-tiles per head
    const int r16 = lane & 15;
    const int q4 = lane >> 4;
    const int sr = t >> 3;
    const int sc = t & 7;

    half8 aq[2][2];
    const int q0 = qt * 128 + w * 32;
    #pragma unroll
    for (int mi = 0; mi < 2; ++mi)
        #pragma unroll
        for (int kk = 0; kk < 2; ++kk)
            aq[mi][kk] = *(const half8*)&Q[hb + (size_t)(q0 + mi * 16 + r16) * 64 + kk * 32 + q4 * 8];

    f32x4 o[4][2];         // O^T accumulator: [ni = d-block][mi = q-block]
    float lsum[2] = {0.f, 0.f};
    #pragma unroll
    for (int ni = 0; ni < 4; ++ni)
        #pragma unroll
        for (int mi = 0; mi < 2; ++mi)
            o[ni][mi] = zero4();

    const int R0 = sr, R1 = 32 + sr;
    const int scs0 = (sc ^ (R0 & 7)) * 8;
    const int scs1 = (sc ^ (R1 & 7)) * 8;

    {   // prologue: stage tile 0 into buffer 0
        gload_lds16(&K[hb + (size_t)R0 * 64 + scs0],  &Ks[0][t * 8]);
        gload_lds16(&K[hb + (size_t)R1 * 64 + scs1],  &Ks[0][2048 + t * 8]);
        gload_lds16(&V4[hb + t * 8],                  &Vs[0][t * 8]);
        gload_lds16(&V4[hb + 2048 + t * 8],           &Vs[0][2048 + t * 8]);
    }
    __syncthreads();

    int pb = 0;
    for (int kt = 0; kt < 32; ++kt) {
        if (kt + 1 < 32) {
            const size_t tb = hb + (size_t)(kt + 1) * 4096;
            gload_lds16(&K[tb + (size_t)R0 * 64 + scs0],  &Ks[pb ^ 1][t * 8]);
            gload_lds16(&K[tb + (size_t)R1 * 64 + scs1],  &Ks[pb ^ 1][2048 + t * 8]);
            gload_lds16(&V4[tb + t * 8],                  &Vs[pb ^ 1][t * 8]);
            gload_lds16(&V4[tb + 2048 + t * 8],           &Vs[pb ^ 1][2048 + t * 8]);
        }

        // S^T = K Q^T: lane holds S^T[16ki+4q4+i][16mi+r16]
        f32x4 sT[4][2];
        #pragma unroll
        for (int ki = 0; ki < 4; ++ki)
            #pragma unroll
            for (int mi = 0; mi < 2; ++mi)
                sT[ki][mi] = zero4();
        __builtin_amdgcn_s_setprio(1);
        #pragma unroll
        for (int kk = 0; kk < 2; ++kk) {
            half8 ak[4];
            #pragma unroll
            for (int ki = 0; ki < 4; ++ki)
                ak[ki] = lds_read8_swz(Ks[pb], ki * 16 + r16, (kk * 32 + q4 * 8) * 2);
            #pragma unroll
            for (int ki = 0; ki < 4; ++ki)
                #pragma unroll
                for (int mi = 0; mi < 2; ++mi)
                    sT[ki][mi] = __builtin_amdgcn_mfma_f32_16x16x32_f16(ak[ki], aq[mi][kk], sT[ki][mi], 0, 0, 0);
        }
        __builtin_amdgcn_s_setprio(0);

        // softmax-lite in-register: p = 2^s, row sums, pack to f16.
        half4 pT[4][2];
        #pragma unroll
        for (int ki = 0; ki < 4; ++ki)
            #pragma unroll
            for (int mi = 0; mi < 2; ++mi) {
                const float p0 = fast_exp2(sT[ki][mi][0]);
                const float p1 = fast_exp2(sT[ki][mi][1]);
                const float p2 = fast_exp2(sT[ki][mi][2]);
                const float p3 = fast_exp2(sT[ki][mi][3]);
                lsum[mi] += (p0 + p1) + (p2 + p3);
                half4 pv;
                pv[0] = (_Float16)p0; pv[1] = (_Float16)p1;
                pv[2] = (_Float16)p2; pv[3] = (_Float16)p3;
                pT[ki][mi] = pv;
            }

        // O^T += V^T P^T
        __builtin_amdgcn_s_setprio(1);
        #pragma unroll
        for (int ki = 0; ki < 4; ++ki)
            #pragma unroll
            for (int ni = 0; ni < 4; ++ni) {
                const half4 av = *(const half4*)&Vs[pb][(ki * 4 + q4) * 256 + (ni * 16 + r16) * 4];
                #pragma unroll
                for (int mi = 0; mi < 2; ++mi)
                    o[ni][mi] = mfma16(av, pT[ki][mi], o[ni][mi]);
            }
        __builtin_amdgcn_s_setprio(0);

        __syncthreads();   // drains prefetch vmcnt + guards K/V buffer reuse
        pb ^= 1;
    }

    float inv[2];
    #pragma unroll
    for (int mi = 0; mi < 2; ++mi) {
        float l = lsum[mi];
        l += __shfl_xor(l, 16);
        l += __shfl_xor(l, 32);
        inv[mi] = 1.f / l;
    }
    #pragma unroll
    for (int mi = 0; mi < 2; ++mi) {
        const int q = q0 + mi * 16 + r16;
        #pragma unroll
        for (int ni = 0; ni < 4; ++ni) {
            half4 ov;
            #pragma unroll
            for (int i = 0; i < 4; ++i)
                ov[i] = (_Float16)(o[ni][mi][i] * inv[mi]);
            *(half4*)&O[hb + (size_t)q * 64 + ni * 16 + q4 * 4] = ov;
        }
    }
}

// ---------------- launcher ----------------
extern "C" void kernel_launch(void* const* d_in, const int* in_sizes, int n_in,
                              void* d_out, int out_size, void* d_ws, size_t ws_size,
                              hipStream_t stream) {
    const float* x  = (const float*)d_in[0];
    const float* Wq = (const float*)d_in[1];
    const float* Wk = (const float*)d_in[2];
    const float* Wv = (const float*)d_in[3];
    const float* Wo = (const float*)d_in[4];

    const size_t XSZ = (size_t)8192 * 1024;   // 8388608 elements
    const size_t WSZ = (size_t)1024 * 1024;

    _Float16* ws  = (_Float16*)d_ws;
    _Float16* xh  = ws;                 // x f16; reused as V4 after QKV
    _Float16* wqh = ws + XSZ;
    _Float16* wkh = wqh + WSZ;
    _Float16* wvh = wkh + WSZ;
    _Float16* woh = wvh + WSZ;
    _Float16* qh  = woh + WSZ;
    _Float16* kh  = qh + XSZ;
    _Float16* vh  = kh + XSZ;
    _Float16* aoh = vh + XSZ;
    _Float16* v4h = xh;                 // alias: x dead after QKV projection

    f2h_kernel<<<XSZ / 4 / 256, 256, 0, stream>>>(x,  xh);
    f2h_kernel<<<WSZ / 4 / 256, 256, 0, stream>>>(Wq, wqh);
    f2h_kernel<<<WSZ / 4 / 256, 256, 0, stream>>>(Wk, wkh);
    f2h_kernel<<<WSZ / 4 / 256, 256, 0, stream>>>(Wv, wvh);
    f2h_kernel<<<WSZ / 4 / 256, 256, 0, stream>>>(Wo, woh);

    // Q scale: (1/sqrt(64)) * log2(e) so attention can use exp2 directly
    const float qscale = 0.125f * 1.44269504088896340736f;

    gemm8<<<384, 512, 0, stream>>>(xh, wqh, qh, qscale);          // fused QKV, 8-phase

    repack_v<<<dim3(32, 64), 256, 0, stream>>>(vh, v4h);

    attn_kernel<<<1024, 256, 0, stream>>>(qh, kh, v4h, aoh);

    gemm_wo<<<512, 256, 0, stream>>>(aoh, woh, (float*)d_out);    // Wo, proven 2-phase
    (void)in_sizes; (void)n_in; (void)out_size; (void)ws_size;
}